// Round 17
// baseline (146.875 us; speedup 1.0000x reference)
//
#include <hip/hip_runtime.h>

// Problem constants
#define HDIM 64
#define LSEQ 2048
#define BATCH 16
#define LN_EPS 1e-5f
#define D_EPS 1e-6f
#define NSEG 32      // segments per batch (64 tokens per block)
#define CPS 4        // chunks per segment (16 tokens each)

typedef unsigned short u16;
typedef unsigned int   u32;

__device__ __forceinline__ float bf2f(u16 v) {
    return __uint_as_float(((u32)v) << 16);
}
__device__ __forceinline__ u16 f2bf(float f) {   // round-to-nearest-even
    u32 u = __float_as_uint(f);
    return (u16)((u + 0x7FFFu + ((u >> 16) & 1u)) >> 16);
}

// ---------------- shared-memory overlay (bytes), total 80736 ----------------
// 2 blocks/CU: 2 x 80736 = 161472 <= 163840.
#define A_SW1   0        // bf16[64*132]  16896
#define A_SW2   16896    // bf16[128*68]  17408
#define A_ET    34304    // f32 [64*68]   17408
#define A_HIDT  51712    // bf16[128*68]  17408
#define A_RED1  69120    // f32 [4*66]    1056
#define A_RED2  70176    // f32 [4*66]    1056
#define A_SMU   71232    // f32 [66]      272
#define A_SRSTD 71504    // f32 [66]      272
#define H_ROWS  71776    // bf16[64*68]   8704   (bf16 h — lossless, h is bf16-rounded)
#define H_INVD  80480    // f32 [64]      256
#define SMEM_BYTES 80736
#define C_S     0        // f32[64*68]   17408
#define C_V     17408    // f32[64*68]   17408
#define C_BM    34816    // f32[16*68]   4352
#define C_Z     39168    // f32[16*68]   4352
#define C_GM    43520    // f32[16*17]   1088

// ---------------------------------------------------------------------------
// Kernel A: fused preprocess + segment composition (byte-identical to R16).
// 512 blocks (b, s in 0..31), 64 tokens/block, 80.7 KB LDS -> 2 blocks/CU.
// ---------------------------------------------------------------------------
__global__ __launch_bounds__(256, 2) void fused_pc_kernel(
    const int* __restrict__ seq, const float* __restrict__ embed,
    const float* __restrict__ W1, const float* __restrict__ b1,
    const float* __restrict__ W2, const float* __restrict__ b2,
    const float* __restrict__ gamma, const float* __restrict__ beta,
    u32* __restrict__ PK, u16* __restrict__ q_ws)
{
    __shared__ __align__(16) char smem[SMEM_BYTES];
    const int t = threadIdx.x;
    const int b = blockIdx.x >> 5;
    const int s = blockIdx.x & 31;
    const int tok0 = 1984 - 64 * s;           // first token of this block

    u16*   hrows  = (u16*)(smem + H_ROWS);
    float* invd_l = (float*)(smem + H_INVD);

    // ======================= Phase A: preprocess ==========================
    {
        u16*   sW1   = (u16*)(smem + A_SW1);
        u16*   sW2   = (u16*)(smem + A_SW2);
        float* eT    = (float*)(smem + A_ET);
        u16*   hidT  = (u16*)(smem + A_HIDT);
        float* red1  = (float*)(smem + A_RED1);
        float* red2  = (float*)(smem + A_RED2);
        float* smu   = (float*)(smem + A_SMU);
        float* srstd = (float*)(smem + A_SRSTD);

        // stage W1 (64x128) and W2 (128x64) as bf16
        {
            const float4* s1 = (const float4*)W1;   // 2048 float4
#pragma unroll
            for (int q = 0; q < 8; ++q) {
                const int m = t + 256 * q;
                const int row = m >> 5, col = m & 31;
                const float4 v = s1[m];
                ushort4 w;
                w.x = f2bf(v.x); w.y = f2bf(v.y); w.z = f2bf(v.z); w.w = f2bf(v.w);
                *(ushort4*)&sW1[row * 132 + col * 4] = w;
            }
            const float4* s2 = (const float4*)W2;   // 2048 float4
#pragma unroll
            for (int q = 0; q < 8; ++q) {
                const int m = t + 256 * q;
                const int row = m >> 4, col = m & 15;
                const float4 v = s2[m];
                ushort4 w;
                w.x = f2bf(v.x); w.y = f2bf(v.y); w.z = f2bf(v.z); w.w = f2bf(v.w);
                *(ushort4*)&sW2[row * 68 + col * 4] = w;
            }
        }
        // stage embeddings transposed: thread (tk = t>>2, p = t&3)
        {
            const int tk = t >> 2, p = t & 3;
            const int v = seq[b * LSEQ + tok0 + tk];
            const float* er = embed + v * HDIM + 16 * p;
#pragma unroll
            for (int q = 0; q < 4; ++q) {
                const float4 ev = *(const float4*)(er + 4 * q);
                const int d = 16 * p + 4 * q;
                eT[(d + 0) * 68 + tk] = ev.x;
                eT[(d + 1) * 68 + tk] = ev.y;
                eT[(d + 2) * 68 + tk] = ev.z;
                eT[(d + 3) * 68 + tk] = ev.w;
            }
        }
        __syncthreads();

        const int r = t >> 4;   // token quad
        const int c = t & 15;   // out quad

        // MLP1: hid = relu(e W1 + b1), bf16 weights, bf16 hid store
        {
            float acc0[4][4], acc1[4][4];
#pragma unroll
            for (int o = 0; o < 4; ++o) {
                const float bA = b1[4 * c + o];
                const float bB = b1[64 + 4 * c + o];
#pragma unroll
                for (int j = 0; j < 4; ++j) { acc0[j][o] = bA; acc1[j][o] = bB; }
            }
            for (int k = 0; k < 64; ++k) {
                const float4  ev = *(const float4*)&eT[k * 68 + 4 * r];
                const ushort4 wa = *(const ushort4*)&sW1[k * 132 + 4 * c];
                const ushort4 wb = *(const ushort4*)&sW1[k * 132 + 64 + 4 * c];
                const float e4[4] = {ev.x, ev.y, ev.z, ev.w};
                const float a4[4] = {bf2f(wa.x), bf2f(wa.y), bf2f(wa.z), bf2f(wa.w)};
                const float b4[4] = {bf2f(wb.x), bf2f(wb.y), bf2f(wb.z), bf2f(wb.w)};
#pragma unroll
                for (int j = 0; j < 4; ++j)
#pragma unroll
                    for (int o = 0; o < 4; ++o) {
                        acc0[j][o] = fmaf(e4[j], a4[o], acc0[j][o]);
                        acc1[j][o] = fmaf(e4[j], b4[o], acc1[j][o]);
                    }
            }
#pragma unroll
            for (int o = 0; o < 4; ++o) {
                ushort4 v0, v1;
                v0.x = f2bf(fmaxf(acc0[0][o], 0.f)); v0.y = f2bf(fmaxf(acc0[1][o], 0.f));
                v0.z = f2bf(fmaxf(acc0[2][o], 0.f)); v0.w = f2bf(fmaxf(acc0[3][o], 0.f));
                *(ushort4*)&hidT[(4 * c + o) * 68 + 4 * r] = v0;
                v1.x = f2bf(fmaxf(acc1[0][o], 0.f)); v1.y = f2bf(fmaxf(acc1[1][o], 0.f));
                v1.z = f2bf(fmaxf(acc1[2][o], 0.f)); v1.w = f2bf(fmaxf(acc1[3][o], 0.f));
                *(ushort4*)&hidT[(64 + 4 * c + o) * 68 + 4 * r] = v1;
            }
        }
        __syncthreads();

        // MLP2: ff = hid W2 + b2; x = e + ff in place into eT
        {
            float acc[4][4];
#pragma unroll
            for (int o = 0; o < 4; ++o) {
                const float bv = b2[4 * c + o];
#pragma unroll
                for (int j = 0; j < 4; ++j) acc[j][o] = bv;
            }
            for (int k = 0; k < 128; ++k) {
                const ushort4 hv = *(const ushort4*)&hidT[k * 68 + 4 * r];
                const ushort4 wv = *(const ushort4*)&sW2[k * 68 + 4 * c];
                const float h4[4] = {bf2f(hv.x), bf2f(hv.y), bf2f(hv.z), bf2f(hv.w)};
                const float w4[4] = {bf2f(wv.x), bf2f(wv.y), bf2f(wv.z), bf2f(wv.w)};
#pragma unroll
                for (int j = 0; j < 4; ++j)
#pragma unroll
                    for (int o = 0; o < 4; ++o)
                        acc[j][o] = fmaf(h4[j], w4[o], acc[j][o]);
            }
#pragma unroll
            for (int o = 0; o < 4; ++o) {
                float4 ex = *(float4*)&eT[(4 * c + o) * 68 + 4 * r];
                ex.x += acc[0][o];
                ex.y += acc[1][o];
                ex.z += acc[2][o];
                ex.w += acc[3][o];
                *(float4*)&eT[(4 * c + o) * 68 + 4 * r] = ex;
            }
        }
        __syncthreads();

        // LN stats
        {
            const int tk = t & 63, p = t >> 6;
            float sv = 0.f, q = 0.f;
#pragma unroll
            for (int i = 0; i < 16; ++i) {
                const float x = eT[(16 * p + i) * 68 + tk];
                sv += x;
                q = fmaf(x, x, q);
            }
            red1[p * 66 + tk] = sv;
            red2[p * 66 + tk] = q;
        }
        __syncthreads();
        if (t < 64) {
            const float sv = ((red1[0 * 66 + t] + red1[1 * 66 + t]) + (red1[2 * 66 + t] + red1[3 * 66 + t]));
            const float qq = ((red2[0 * 66 + t] + red2[1 * 66 + t]) + (red2[2 * 66 + t] + red2[3 * 66 + t]));
            const float mu  = sv * (1.0f / 64.0f);
            const float var = qq * (1.0f / 64.0f) - mu * mu;
            smu[t]   = mu;
            srstd[t] = 1.0f / sqrtf(var + LN_EPS);
        }
        __syncthreads();

        // normalize, round bf16, store bf16 into hrows; hh over ROUNDED
        // values; block (b, s=0) local row 63 = token 2047 exports q
        {
            const int tk = t >> 2, p = t & 3;
            const float mu = smu[tk], rstd = srstd[tk];
            float hh = 0.f;
#pragma unroll
            for (int i2 = 0; i2 < 8; ++i2) {
                const int d = 16 * p + 2 * i2;
                const float x0 = eT[(d + 0) * 68 + tk];
                const float x1 = eT[(d + 1) * 68 + tk];
                const float o0 = (x0 - mu) * rstd * gamma[d + 0] + beta[d + 0];
                const float o1 = (x1 - mu) * rstd * gamma[d + 1] + beta[d + 1];
                const u16 r0 = f2bf(o0), r1 = f2bf(o1);
                const float q0f = bf2f(r0), q1f = bf2f(r1);
                hh = fmaf(q0f, q0f, hh);
                hh = fmaf(q1f, q1f, hh);
                *(u32*)&hrows[tk * 68 + d] = (u32)r0 | ((u32)r1 << 16);
                if (s == 0 && tk == 63) {   // token 2047: export q
                    q_ws[b * 64 + d]     = r0;
                    q_ws[b * 64 + d + 1] = r1;
                }
            }
            red1[p * 66 + tk] = hh;
        }
        __syncthreads();
        if (t < 64) {
            const float hh = ((red1[0 * 66 + t] + red1[1 * 66 + t]) + (red1[2 * 66 + t] + red1[3 * 66 + t]));
            invd_l[t] = 1.0f / (hh + D_EPS);
        }
    }
    __syncthreads();

    // zero the sigma=0 padded key (local row 63 = token 2047, only segment 0)
    if (s == 0 && t < 64) hrows[63 * 68 + t] = 0;

    // ======================= Phase B: compose =============================
    {
        float* S  = (float*)(smem + C_S);
        float* V  = (float*)(smem + C_V);
        float* Bm = (float*)(smem + C_BM);
        float* Z  = (float*)(smem + C_Z);
        float* Gm = (float*)(smem + C_GM);

        // init S = I, V = 0
        for (int idx = t; idx < 64 * 64; idx += 256) {
            const int m = idx >> 6, n = idx & 63;
            S[m * 68 + n] = (m == n) ? 1.0f : 0.0f;
            V[m * 68 + n] = 0.0f;
        }

        for (int cc = 0; cc < CPS; ++cc) {
            const int base = 63 - 16 * cc;   // hrows row of solve-slot j is base-j
            __syncthreads();   // init / previous chunk reads done

            // Gram: Gm[i][j] = (k_i . k_j) * invd[base-j], i > j
            {
                const int i = t >> 4, j = t & 15;
                if (i > j) {
                    const u16* ra = &hrows[(base - i) * 68];
                    const u16* rb = &hrows[(base - j) * 68];
                    float acc = 0.f;
#pragma unroll
                    for (int m = 0; m < 64; m += 4) {
                        const ushort4 a4 = *(const ushort4*)&ra[m];
                        const ushort4 b4 = *(const ushort4*)&rb[m];
                        acc += bf2f(a4.x) * bf2f(b4.x) + bf2f(a4.y) * bf2f(b4.y)
                             + bf2f(a4.z) * bf2f(b4.z) + bf2f(a4.w) * bf2f(b4.w);
                    }
                    Gm[i * 17 + j] = acc * invd_l[base - j];
                }
            }
            __syncthreads();

            // B: forward substitution L B = K (wave 0)
            if (t < 64) {
                const int n = t;
                float Breg[16];
#pragma unroll
                for (int i = 0; i < 16; ++i) {
                    float acc = bf2f(hrows[(base - i) * 68 + n]);
#pragma unroll
                    for (int j = 0; j < 16; ++j)
                        if (j < i) acc = fmaf(-Gm[i * 17 + j], Breg[j], acc);
                    Breg[i] = acc;
                    Bm[i * 68 + n] = acc;
                }
            }
            __syncthreads();

            // Z = B S
            {
                const int i  = t & 15;
                const int n0 = (t >> 4) * 4;
                float4 z = make_float4(0.f, 0.f, 0.f, 0.f);
#pragma unroll
                for (int mq = 0; mq < 16; ++mq) {
                    const float4 bq = *(const float4*)&Bm[i * 68 + mq * 4];
                    const float4 s0 = *(const float4*)&S[(mq * 4 + 0) * 68 + n0];
                    const float4 s1 = *(const float4*)&S[(mq * 4 + 1) * 68 + n0];
                    const float4 s2 = *(const float4*)&S[(mq * 4 + 2) * 68 + n0];
                    const float4 s3 = *(const float4*)&S[(mq * 4 + 3) * 68 + n0];
                    z.x = fmaf(bq.x, s0.x, fmaf(bq.y, s1.x, fmaf(bq.z, s2.x, fmaf(bq.w, s3.x, z.x))));
                    z.y = fmaf(bq.x, s0.y, fmaf(bq.y, s1.y, fmaf(bq.z, s2.y, fmaf(bq.w, s3.y, z.y))));
                    z.z = fmaf(bq.x, s0.z, fmaf(bq.y, s1.z, fmaf(bq.z, s2.z, fmaf(bq.w, s3.z, z.z))));
                    z.w = fmaf(bq.x, s0.w, fmaf(bq.y, s1.w, fmaf(bq.z, s2.w, fmaf(bq.w, s3.w, z.w))));
                }
                *(float4*)&Z[i * 68 + n0] = z;
            }
            __syncthreads();

            // S -= K^T (ivd_j * Z) ; V += K^T Z   (ztq inline)
            {
                const int n0 = (t & 15) * 4;
                const int mh = t >> 4;
                float iv16[16];
#pragma unroll
                for (int q4 = 0; q4 < 4; ++q4) {
                    const float4 v4 = *(const float4*)&invd_l[base - 15 + 4 * q4];
                    iv16[15 - 4 * q4]     = v4.x;
                    iv16[15 - 4 * q4 - 1] = v4.y;
                    iv16[15 - 4 * q4 - 2] = v4.z;
                    iv16[15 - 4 * q4 - 3] = v4.w;
                }
                float4 sacc[4], vacc[4];
#pragma unroll
                for (int p = 0; p < 4; ++p) {
                    sacc[p] = *(float4*)&S[(mh + 16 * p) * 68 + n0];
                    vacc[p] = *(float4*)&V[(mh + 16 * p) * 68 + n0];
                }
#pragma unroll
                for (int j = 0; j < 16; ++j) {
                    const float4 zq = *(const float4*)&Z[j * 68 + n0];
                    const float iv = iv16[j];
                    float4 ztq;
                    ztq.x = zq.x * iv; ztq.y = zq.y * iv;
                    ztq.z = zq.z * iv; ztq.w = zq.w * iv;
                    const u16* kr = &hrows[(base - j) * 68];
                    const float k0 = bf2f(kr[mh]);
                    const float k1 = bf2f(kr[mh + 16]);
                    const float k2 = bf2f(kr[mh + 32]);
                    const float k3 = bf2f(kr[mh + 48]);
                    vacc[0].x = fmaf(k0, zq.x, vacc[0].x); vacc[0].y = fmaf(k0, zq.y, vacc[0].y);
                    vacc[0].z = fmaf(k0, zq.z, vacc[0].z); vacc[0].w = fmaf(k0, zq.w, vacc[0].w);
                    vacc[1].x = fmaf(k1, zq.x, vacc[1].x); vacc[1].y = fmaf(k1, zq.y, vacc[1].y);
                    vacc[1].z = fmaf(k1, zq.z, vacc[1].z); vacc[1].w = fmaf(k1, zq.w, vacc[1].w);
                    vacc[2].x = fmaf(k2, zq.x, vacc[2].x); vacc[2].y = fmaf(k2, zq.y, vacc[2].y);
                    vacc[2].z = fmaf(k2, zq.z, vacc[2].z); vacc[2].w = fmaf(k2, zq.w, vacc[2].w);
                    vacc[3].x = fmaf(k3, zq.x, vacc[3].x); vacc[3].y = fmaf(k3, zq.y, vacc[3].y);
                    vacc[3].z = fmaf(k3, zq.z, vacc[3].z); vacc[3].w = fmaf(k3, zq.w, vacc[3].w);
                    sacc[0].x = fmaf(-k0, ztq.x, sacc[0].x); sacc[0].y = fmaf(-k0, ztq.y, sacc[0].y);
                    sacc[0].z = fmaf(-k0, ztq.z, sacc[0].z); sacc[0].w = fmaf(-k0, ztq.w, sacc[0].w);
                    sacc[1].x = fmaf(-k1, ztq.x, sacc[1].x); sacc[1].y = fmaf(-k1, ztq.y, sacc[1].y);
                    sacc[1].z = fmaf(-k1, ztq.z, sacc[1].z); sacc[1].w = fmaf(-k1, ztq.w, sacc[1].w);
                    sacc[2].x = fmaf(-k2, ztq.x, sacc[2].x); sacc[2].y = fmaf(-k2, ztq.y, sacc[2].y);
                    sacc[2].z = fmaf(-k2, ztq.z, sacc[2].z); sacc[2].w = fmaf(-k2, ztq.w, sacc[2].w);
                    sacc[3].x = fmaf(-k3, ztq.x, sacc[3].x); sacc[3].y = fmaf(-k3, ztq.y, sacc[3].y);
                    sacc[3].z = fmaf(-k3, ztq.z, sacc[3].z); sacc[3].w = fmaf(-k3, ztq.w, sacc[3].w);
                }
#pragma unroll
                for (int p = 0; p < 4; ++p) {
                    *(float4*)&S[(mh + 16 * p) * 68 + n0] = sacc[p];
                    *(float4*)&V[(mh + 16 * p) * 68 + n0] = vacc[p];
                }
            }
        }
        __syncthreads();

        // writeback: pk[j*64+i] = pack(bf16(S[i][j]), bf16(V[i][j]))
        u32* pk = PK + ((size_t)(b * NSEG + s) << 12);
        for (int idx = t; idx < 4096; idx += 256) {
            const int j = idx >> 6, i = idx & 63;
            const u32 sb = ((u32)f2bf(S[i * 68 + j])) << 16;
            const u32 vb = (u32)f2bf(V[i * 68 + j]);
            pk[idx] = sb | vb;
        }
    }
}

// ---------------------------------------------------------------------------
// Kernel B: serial segment pass + output projection. R17: grid 64 —
// blocks 0..15 are the per-batch workers (math bit-identical to R16) with a
// DEPTH-4 register pipeline (loads issued ~3 segments / ~1000 cyc before
// use); blocks 16..63 are L3 warmers that stream all of PK into the shared
// Infinity Cache so the workers' misses become L3 hits.
// ---------------------------------------------------------------------------
__global__ __launch_bounds__(256, 1) void final_kernel(
    const u16* __restrict__ q_ws, const u32* __restrict__ PK,
    const float* __restrict__ Wr, const float* __restrict__ br,
    const float* __restrict__ Wo, const float* __restrict__ bo,
    float* __restrict__ out, u32* __restrict__ sink)
{
    const int t = threadIdx.x;

    if (blockIdx.x >= BATCH) {
        // ---- L3 warmer: stream PK (coalesced), xor-reduce, guarded store
        const int wid = blockIdx.x - BATCH;          // 0..47
        const int total = BATCH * NSEG * 4096;       // 2,097,152 u32
        u32 acc = 0;
        for (int i = wid * 256 + t; i < total; i += 48 * 256)
            acc ^= PK[i];
        if (acc == 0xDEADBEEFu) *sink = acc;         // never-taken in practice
        return;
    }

    const int b    = blockIdx.x;
    const int lane = t & 63;
    const int p    = t >> 6;         // wave id = j-slice

    __shared__ float psum[4][72];
    __shared__ float rl[64];
    __shared__ float cs[64], rs[64];

    rl[lane] = bf2f(q_ws[b * 64 + lane]);

    float ctxp = 0.f;

    u32 bA[16], bB[16], bC[16], bD[16];
    auto ldseg = [&](int sg, u32 (&buf)[16]) {
        const u32* pk = PK + ((size_t)(b * NSEG + sg) << 12);
#pragma unroll
        for (int jj = 0; jj < 16; ++jj)
            buf[jj] = pk[(p * 16 + jj) * 64 + lane];
    };
    auto compute = [&](u32 (&buf)[16]) {
        float accr = 0.f;
#pragma unroll
        for (int jj = 0; jj < 16; ++jj) {
            const u32 pv = buf[jj];
            const float Sv = __uint_as_float(pv & 0xFFFF0000u);
            const float Vv = __uint_as_float(pv << 16);
            const float rj = rl[p * 16 + jj];
            accr = fmaf(Sv, rj, accr);
            ctxp = fmaf(Vv, rj, ctxp);
        }
        psum[p][lane] = accr;
        __syncthreads();
        const float rn = (psum[0][lane] + psum[1][lane]) + (psum[2][lane] + psum[3][lane]);
        __syncthreads();
        rl[lane] = rn;           // every wave writes the same full copy
    };

    ldseg(0, bA); ldseg(1, bB); ldseg(2, bC); ldseg(3, bD);
    __syncthreads();

    for (int s = 0; s < NSEG; s += 4) {
        compute(bA); ldseg(min(s + 4, NSEG - 1), bA);
        compute(bB); ldseg(min(s + 5, NSEG - 1), bB);
        compute(bC); ldseg(min(s + 6, NSEG - 1), bC);
        compute(bD); ldseg(min(s + 7, NSEG - 1), bD);
    }

    // ---- epilogue: out[b] = (ctx Wr + br) Wo + bo ----
    psum[p][lane] = ctxp;
    __syncthreads();
    if (t < 64)
        cs[t] = (psum[0][t] + psum[1][t]) + (psum[2][t] + psum[3][t]);
    __syncthreads();

    float rv = (p == 0) ? br[lane] : 0.f;
#pragma unroll
    for (int i = 0; i < 16; ++i)
        rv = fmaf(cs[p * 16 + i], Wr[(p * 16 + i) * HDIM + lane], rv);
    psum[p][lane] = rv;
    __syncthreads();
    if (t < 64)
        rs[t] = (psum[0][t] + psum[1][t]) + (psum[2][t] + psum[3][t]);
    __syncthreads();

    float ov = (p == 0) ? bo[lane] : 0.f;
#pragma unroll
    for (int i = 0; i < 16; ++i)
        ov = fmaf(rs[p * 16 + i], Wo[(p * 16 + i) * HDIM + lane], ov);
    psum[p][lane] = ov;
    __syncthreads();
    if (t < 64)
        out[(size_t)b * HDIM + t] = (psum[0][t] + psum[1][t]) + (psum[2][t] + psum[3][t]);
}

// ---------------------------------------------------------------------------
extern "C" void kernel_launch(void* const* d_in, const int* in_sizes, int n_in,
                              void* d_out, int out_size, void* d_ws, size_t ws_size,
                              hipStream_t stream)
{
    const int*   seq   = (const int*)  d_in[0];
    const float* embed = (const float*)d_in[1];
    const float* W1    = (const float*)d_in[2];
    const float* b1    = (const float*)d_in[3];
    const float* W2    = (const float*)d_in[4];
    const float* b2    = (const float*)d_in[5];
    const float* gamma = (const float*)d_in[6];
    const float* beta  = (const float*)d_in[7];
    const float* Wr    = (const float*)d_in[8];
    const float* br    = (const float*)d_in[9];
    const float* Wo    = (const float*)d_in[10];
    const float* bo    = (const float*)d_in[11];

    u32* pk_ws = (u32*)d_ws;                                  // 8 MB (16*32*4096 u32)
    u16* q_ws  = (u16*)(pk_ws + (size_t)BATCH * NSEG * 4096); // 2 KB
    u32* sink  = (u32*)(q_ws + BATCH * HDIM);                 // 4 B
    float* outp = (float*)d_out;

    hipLaunchKernelGGL(fused_pc_kernel, dim3(BATCH * NSEG), dim3(256), 0, stream,
                       seq, embed, W1, b1, W2, b2, gamma, beta, pk_ws, q_ws);
    hipLaunchKernelGGL(final_kernel, dim3(64), dim3(256), 0, stream,
                       q_ws, pk_ws, Wr, br, Wo, bo, outp, sink);
}

// Round 18
// 139.704 us; speedup vs baseline: 1.0513x; 1.0513x over previous
//
#include <hip/hip_runtime.h>

// Problem constants
#define HDIM 64
#define LSEQ 2048
#define BATCH 16
#define LN_EPS 1e-5f
#define D_EPS 1e-6f
#define NSEG 32      // segments per batch (64 tokens per block)
#define CPS 4        // chunks per segment (16 tokens each)

typedef unsigned short u16;
typedef unsigned int   u32;

__device__ __forceinline__ float bf2f(u16 v) {
    return __uint_as_float(((u32)v) << 16);
}
__device__ __forceinline__ u16 f2bf(float f) {   // round-to-nearest-even
    u32 u = __float_as_uint(f);
    return (u16)((u + 0x7FFFu + ((u >> 16) & 1u)) >> 16);
}

// ---------------- shared-memory overlay (bytes), total 80736 ----------------
// 2 blocks/CU: 2 x 80736 = 161472 <= 163840.
#define A_SW1   0        // bf16[64*132]  16896
#define A_SW2   16896    // bf16[128*68]  17408
#define A_ET    34304    // f32 [64*68]   17408
#define A_HIDT  51712    // bf16[128*68]  17408
#define A_RED1  69120    // f32 [4*66]    1056
#define A_RED2  70176    // f32 [4*66]    1056
#define A_SMU   71232    // f32 [66]      272
#define A_SRSTD 71504    // f32 [66]      272
#define H_ROWS  71776    // bf16[64*68]   8704   (bf16 h — lossless, h is bf16-rounded)
#define H_INVD  80480    // f32 [64]      256
#define SMEM_BYTES 80736
#define C_S     0        // f32[64*68]   17408
#define C_V     17408    // f32[64*68]   17408
#define C_BM    34816    // f32[16*68]   4352
#define C_Z     39168    // f32[16*68]   4352
#define C_GM    43520    // f32[16*17]   1088

// ---------------------------------------------------------------------------
// Kernel A: fused preprocess + segment composition (byte-identical to R16).
// 512 blocks (b, s in 0..31), 64 tokens/block, 80.7 KB LDS -> 2 blocks/CU
// co-resident (independent blocks overlap each other's LDS/barrier stalls).
// ---------------------------------------------------------------------------
__global__ __launch_bounds__(256, 2) void fused_pc_kernel(
    const int* __restrict__ seq, const float* __restrict__ embed,
    const float* __restrict__ W1, const float* __restrict__ b1,
    const float* __restrict__ W2, const float* __restrict__ b2,
    const float* __restrict__ gamma, const float* __restrict__ beta,
    u32* __restrict__ PK, u16* __restrict__ q_ws)
{
    __shared__ __align__(16) char smem[SMEM_BYTES];
    const int t = threadIdx.x;
    const int b = blockIdx.x >> 5;
    const int s = blockIdx.x & 31;
    const int tok0 = 1984 - 64 * s;           // first token of this block

    u16*   hrows  = (u16*)(smem + H_ROWS);
    float* invd_l = (float*)(smem + H_INVD);

    // ======================= Phase A: preprocess ==========================
    {
        u16*   sW1   = (u16*)(smem + A_SW1);
        u16*   sW2   = (u16*)(smem + A_SW2);
        float* eT    = (float*)(smem + A_ET);
        u16*   hidT  = (u16*)(smem + A_HIDT);
        float* red1  = (float*)(smem + A_RED1);
        float* red2  = (float*)(smem + A_RED2);
        float* smu   = (float*)(smem + A_SMU);
        float* srstd = (float*)(smem + A_SRSTD);

        // stage W1 (64x128) and W2 (128x64) as bf16
        {
            const float4* s1 = (const float4*)W1;   // 2048 float4
#pragma unroll
            for (int q = 0; q < 8; ++q) {
                const int m = t + 256 * q;
                const int row = m >> 5, col = m & 31;
                const float4 v = s1[m];
                ushort4 w;
                w.x = f2bf(v.x); w.y = f2bf(v.y); w.z = f2bf(v.z); w.w = f2bf(v.w);
                *(ushort4*)&sW1[row * 132 + col * 4] = w;
            }
            const float4* s2 = (const float4*)W2;   // 2048 float4
#pragma unroll
            for (int q = 0; q < 8; ++q) {
                const int m = t + 256 * q;
                const int row = m >> 4, col = m & 15;
                const float4 v = s2[m];
                ushort4 w;
                w.x = f2bf(v.x); w.y = f2bf(v.y); w.z = f2bf(v.z); w.w = f2bf(v.w);
                *(ushort4*)&sW2[row * 68 + col * 4] = w;
            }
        }
        // stage embeddings transposed: thread (tk = t>>2, p = t&3)
        {
            const int tk = t >> 2, p = t & 3;
            const int v = seq[b * LSEQ + tok0 + tk];
            const float* er = embed + v * HDIM + 16 * p;
#pragma unroll
            for (int q = 0; q < 4; ++q) {
                const float4 ev = *(const float4*)(er + 4 * q);
                const int d = 16 * p + 4 * q;
                eT[(d + 0) * 68 + tk] = ev.x;
                eT[(d + 1) * 68 + tk] = ev.y;
                eT[(d + 2) * 68 + tk] = ev.z;
                eT[(d + 3) * 68 + tk] = ev.w;
            }
        }
        __syncthreads();

        const int r = t >> 4;   // token quad
        const int c = t & 15;   // out quad

        // MLP1: hid = relu(e W1 + b1), bf16 weights, bf16 hid store
        {
            float acc0[4][4], acc1[4][4];
#pragma unroll
            for (int o = 0; o < 4; ++o) {
                const float bA = b1[4 * c + o];
                const float bB = b1[64 + 4 * c + o];
#pragma unroll
                for (int j = 0; j < 4; ++j) { acc0[j][o] = bA; acc1[j][o] = bB; }
            }
            for (int k = 0; k < 64; ++k) {
                const float4  ev = *(const float4*)&eT[k * 68 + 4 * r];
                const ushort4 wa = *(const ushort4*)&sW1[k * 132 + 4 * c];
                const ushort4 wb = *(const ushort4*)&sW1[k * 132 + 64 + 4 * c];
                const float e4[4] = {ev.x, ev.y, ev.z, ev.w};
                const float a4[4] = {bf2f(wa.x), bf2f(wa.y), bf2f(wa.z), bf2f(wa.w)};
                const float b4[4] = {bf2f(wb.x), bf2f(wb.y), bf2f(wb.z), bf2f(wb.w)};
#pragma unroll
                for (int j = 0; j < 4; ++j)
#pragma unroll
                    for (int o = 0; o < 4; ++o) {
                        acc0[j][o] = fmaf(e4[j], a4[o], acc0[j][o]);
                        acc1[j][o] = fmaf(e4[j], b4[o], acc1[j][o]);
                    }
            }
#pragma unroll
            for (int o = 0; o < 4; ++o) {
                ushort4 v0, v1;
                v0.x = f2bf(fmaxf(acc0[0][o], 0.f)); v0.y = f2bf(fmaxf(acc0[1][o], 0.f));
                v0.z = f2bf(fmaxf(acc0[2][o], 0.f)); v0.w = f2bf(fmaxf(acc0[3][o], 0.f));
                *(ushort4*)&hidT[(4 * c + o) * 68 + 4 * r] = v0;
                v1.x = f2bf(fmaxf(acc1[0][o], 0.f)); v1.y = f2bf(fmaxf(acc1[1][o], 0.f));
                v1.z = f2bf(fmaxf(acc1[2][o], 0.f)); v1.w = f2bf(fmaxf(acc1[3][o], 0.f));
                *(ushort4*)&hidT[(64 + 4 * c + o) * 68 + 4 * r] = v1;
            }
        }
        __syncthreads();

        // MLP2: ff = hid W2 + b2; x = e + ff in place into eT
        {
            float acc[4][4];
#pragma unroll
            for (int o = 0; o < 4; ++o) {
                const float bv = b2[4 * c + o];
#pragma unroll
                for (int j = 0; j < 4; ++j) acc[j][o] = bv;
            }
            for (int k = 0; k < 128; ++k) {
                const ushort4 hv = *(const ushort4*)&hidT[k * 68 + 4 * r];
                const ushort4 wv = *(const ushort4*)&sW2[k * 68 + 4 * c];
                const float h4[4] = {bf2f(hv.x), bf2f(hv.y), bf2f(hv.z), bf2f(hv.w)};
                const float w4[4] = {bf2f(wv.x), bf2f(wv.y), bf2f(wv.z), bf2f(wv.w)};
#pragma unroll
                for (int j = 0; j < 4; ++j)
#pragma unroll
                    for (int o = 0; o < 4; ++o)
                        acc[j][o] = fmaf(h4[j], w4[o], acc[j][o]);
            }
#pragma unroll
            for (int o = 0; o < 4; ++o) {
                float4 ex = *(float4*)&eT[(4 * c + o) * 68 + 4 * r];
                ex.x += acc[0][o];
                ex.y += acc[1][o];
                ex.z += acc[2][o];
                ex.w += acc[3][o];
                *(float4*)&eT[(4 * c + o) * 68 + 4 * r] = ex;
            }
        }
        __syncthreads();

        // LN stats
        {
            const int tk = t & 63, p = t >> 6;
            float sv = 0.f, q = 0.f;
#pragma unroll
            for (int i = 0; i < 16; ++i) {
                const float x = eT[(16 * p + i) * 68 + tk];
                sv += x;
                q = fmaf(x, x, q);
            }
            red1[p * 66 + tk] = sv;
            red2[p * 66 + tk] = q;
        }
        __syncthreads();
        if (t < 64) {
            const float sv = ((red1[0 * 66 + t] + red1[1 * 66 + t]) + (red1[2 * 66 + t] + red1[3 * 66 + t]));
            const float qq = ((red2[0 * 66 + t] + red2[1 * 66 + t]) + (red2[2 * 66 + t] + red2[3 * 66 + t]));
            const float mu  = sv * (1.0f / 64.0f);
            const float var = qq * (1.0f / 64.0f) - mu * mu;
            smu[t]   = mu;
            srstd[t] = 1.0f / sqrtf(var + LN_EPS);
        }
        __syncthreads();

        // normalize, round bf16, store bf16 into hrows; hh over ROUNDED
        // values; block (b, s=0) local row 63 = token 2047 exports q
        {
            const int tk = t >> 2, p = t & 3;
            const float mu = smu[tk], rstd = srstd[tk];
            float hh = 0.f;
#pragma unroll
            for (int i2 = 0; i2 < 8; ++i2) {
                const int d = 16 * p + 2 * i2;
                const float x0 = eT[(d + 0) * 68 + tk];
                const float x1 = eT[(d + 1) * 68 + tk];
                const float o0 = (x0 - mu) * rstd * gamma[d + 0] + beta[d + 0];
                const float o1 = (x1 - mu) * rstd * gamma[d + 1] + beta[d + 1];
                const u16 r0 = f2bf(o0), r1 = f2bf(o1);
                const float q0f = bf2f(r0), q1f = bf2f(r1);
                hh = fmaf(q0f, q0f, hh);
                hh = fmaf(q1f, q1f, hh);
                *(u32*)&hrows[tk * 68 + d] = (u32)r0 | ((u32)r1 << 16);
                if (s == 0 && tk == 63) {   // token 2047: export q
                    q_ws[b * 64 + d]     = r0;
                    q_ws[b * 64 + d + 1] = r1;
                }
            }
            red1[p * 66 + tk] = hh;
        }
        __syncthreads();
        if (t < 64) {
            const float hh = ((red1[0 * 66 + t] + red1[1 * 66 + t]) + (red1[2 * 66 + t] + red1[3 * 66 + t]));
            invd_l[t] = 1.0f / (hh + D_EPS);
        }
    }
    __syncthreads();

    // zero the sigma=0 padded key (local row 63 = token 2047, only segment 0)
    if (s == 0 && t < 64) hrows[63 * 68 + t] = 0;

    // ======================= Phase B: compose =============================
    {
        float* S  = (float*)(smem + C_S);
        float* V  = (float*)(smem + C_V);
        float* Bm = (float*)(smem + C_BM);
        float* Z  = (float*)(smem + C_Z);
        float* Gm = (float*)(smem + C_GM);

        // init S = I, V = 0
        for (int idx = t; idx < 64 * 64; idx += 256) {
            const int m = idx >> 6, n = idx & 63;
            S[m * 68 + n] = (m == n) ? 1.0f : 0.0f;
            V[m * 68 + n] = 0.0f;
        }

        for (int cc = 0; cc < CPS; ++cc) {
            const int base = 63 - 16 * cc;   // hrows row of solve-slot j is base-j
            __syncthreads();   // init / previous chunk reads done

            // Gram: Gm[i][j] = (k_i . k_j) * invd[base-j], i > j
            {
                const int i = t >> 4, j = t & 15;
                if (i > j) {
                    const u16* ra = &hrows[(base - i) * 68];
                    const u16* rb = &hrows[(base - j) * 68];
                    float acc = 0.f;
#pragma unroll
                    for (int m = 0; m < 64; m += 4) {
                        const ushort4 a4 = *(const ushort4*)&ra[m];
                        const ushort4 b4 = *(const ushort4*)&rb[m];
                        acc += bf2f(a4.x) * bf2f(b4.x) + bf2f(a4.y) * bf2f(b4.y)
                             + bf2f(a4.z) * bf2f(b4.z) + bf2f(a4.w) * bf2f(b4.w);
                    }
                    Gm[i * 17 + j] = acc * invd_l[base - j];
                }
            }
            __syncthreads();

            // B: forward substitution L B = K (wave 0)
            if (t < 64) {
                const int n = t;
                float Breg[16];
#pragma unroll
                for (int i = 0; i < 16; ++i) {
                    float acc = bf2f(hrows[(base - i) * 68 + n]);
#pragma unroll
                    for (int j = 0; j < 16; ++j)
                        if (j < i) acc = fmaf(-Gm[i * 17 + j], Breg[j], acc);
                    Breg[i] = acc;
                    Bm[i * 68 + n] = acc;
                }
            }
            __syncthreads();

            // Z = B S
            {
                const int i  = t & 15;
                const int n0 = (t >> 4) * 4;
                float4 z = make_float4(0.f, 0.f, 0.f, 0.f);
#pragma unroll
                for (int mq = 0; mq < 16; ++mq) {
                    const float4 bq = *(const float4*)&Bm[i * 68 + mq * 4];
                    const float4 s0 = *(const float4*)&S[(mq * 4 + 0) * 68 + n0];
                    const float4 s1 = *(const float4*)&S[(mq * 4 + 1) * 68 + n0];
                    const float4 s2 = *(const float4*)&S[(mq * 4 + 2) * 68 + n0];
                    const float4 s3 = *(const float4*)&S[(mq * 4 + 3) * 68 + n0];
                    z.x = fmaf(bq.x, s0.x, fmaf(bq.y, s1.x, fmaf(bq.z, s2.x, fmaf(bq.w, s3.x, z.x))));
                    z.y = fmaf(bq.x, s0.y, fmaf(bq.y, s1.y, fmaf(bq.z, s2.y, fmaf(bq.w, s3.y, z.y))));
                    z.z = fmaf(bq.x, s0.z, fmaf(bq.y, s1.z, fmaf(bq.z, s2.z, fmaf(bq.w, s3.z, z.z))));
                    z.w = fmaf(bq.x, s0.w, fmaf(bq.y, s1.w, fmaf(bq.z, s2.w, fmaf(bq.w, s3.w, z.w))));
                }
                *(float4*)&Z[i * 68 + n0] = z;
            }
            __syncthreads();

            // S -= K^T (ivd_j * Z) ; V += K^T Z   (ztq inline)
            {
                const int n0 = (t & 15) * 4;
                const int mh = t >> 4;
                float iv16[16];
#pragma unroll
                for (int q4 = 0; q4 < 4; ++q4) {
                    const float4 v4 = *(const float4*)&invd_l[base - 15 + 4 * q4];
                    iv16[15 - 4 * q4]     = v4.x;
                    iv16[15 - 4 * q4 - 1] = v4.y;
                    iv16[15 - 4 * q4 - 2] = v4.z;
                    iv16[15 - 4 * q4 - 3] = v4.w;
                }
                float4 sacc[4], vacc[4];
#pragma unroll
                for (int p = 0; p < 4; ++p) {
                    sacc[p] = *(float4*)&S[(mh + 16 * p) * 68 + n0];
                    vacc[p] = *(float4*)&V[(mh + 16 * p) * 68 + n0];
                }
#pragma unroll
                for (int j = 0; j < 16; ++j) {
                    const float4 zq = *(const float4*)&Z[j * 68 + n0];
                    const float iv = iv16[j];
                    float4 ztq;
                    ztq.x = zq.x * iv; ztq.y = zq.y * iv;
                    ztq.z = zq.z * iv; ztq.w = zq.w * iv;
                    const u16* kr = &hrows[(base - j) * 68];
                    const float k0 = bf2f(kr[mh]);
                    const float k1 = bf2f(kr[mh + 16]);
                    const float k2 = bf2f(kr[mh + 32]);
                    const float k3 = bf2f(kr[mh + 48]);
                    vacc[0].x = fmaf(k0, zq.x, vacc[0].x); vacc[0].y = fmaf(k0, zq.y, vacc[0].y);
                    vacc[0].z = fmaf(k0, zq.z, vacc[0].z); vacc[0].w = fmaf(k0, zq.w, vacc[0].w);
                    vacc[1].x = fmaf(k1, zq.x, vacc[1].x); vacc[1].y = fmaf(k1, zq.y, vacc[1].y);
                    vacc[1].z = fmaf(k1, zq.z, vacc[1].z); vacc[1].w = fmaf(k1, zq.w, vacc[1].w);
                    vacc[2].x = fmaf(k2, zq.x, vacc[2].x); vacc[2].y = fmaf(k2, zq.y, vacc[2].y);
                    vacc[2].z = fmaf(k2, zq.z, vacc[2].z); vacc[2].w = fmaf(k2, zq.w, vacc[2].w);
                    vacc[3].x = fmaf(k3, zq.x, vacc[3].x); vacc[3].y = fmaf(k3, zq.y, vacc[3].y);
                    vacc[3].z = fmaf(k3, zq.z, vacc[3].z); vacc[3].w = fmaf(k3, zq.w, vacc[3].w);
                    sacc[0].x = fmaf(-k0, ztq.x, sacc[0].x); sacc[0].y = fmaf(-k0, ztq.y, sacc[0].y);
                    sacc[0].z = fmaf(-k0, ztq.z, sacc[0].z); sacc[0].w = fmaf(-k0, ztq.w, sacc[0].w);
                    sacc[1].x = fmaf(-k1, ztq.x, sacc[1].x); sacc[1].y = fmaf(-k1, ztq.y, sacc[1].y);
                    sacc[1].z = fmaf(-k1, ztq.z, sacc[1].z); sacc[1].w = fmaf(-k1, ztq.w, sacc[1].w);
                    sacc[2].x = fmaf(-k2, ztq.x, sacc[2].x); sacc[2].y = fmaf(-k2, ztq.y, sacc[2].y);
                    sacc[2].z = fmaf(-k2, ztq.z, sacc[2].z); sacc[2].w = fmaf(-k2, ztq.w, sacc[2].w);
                    sacc[3].x = fmaf(-k3, ztq.x, sacc[3].x); sacc[3].y = fmaf(-k3, ztq.y, sacc[3].y);
                    sacc[3].z = fmaf(-k3, ztq.z, sacc[3].z); sacc[3].w = fmaf(-k3, ztq.w, sacc[3].w);
                }
#pragma unroll
                for (int p = 0; p < 4; ++p) {
                    *(float4*)&S[(mh + 16 * p) * 68 + n0] = sacc[p];
                    *(float4*)&V[(mh + 16 * p) * 68 + n0] = vacc[p];
                }
            }
        }
        __syncthreads();

        // writeback: pk[j*64+i] = pack(bf16(S[i][j]), bf16(V[i][j]))
        u32* pk = PK + ((size_t)(b * NSEG + s) << 12);
        for (int idx = t; idx < 4096; idx += 256) {
            const int j = idx >> 6, i = idx & 63;
            const u32 sb = ((u32)f2bf(S[i * 68 + j])) << 16;
            const u32 vb = (u32)f2bf(V[i * 68 + j]);
            pk[idx] = sb | vb;
        }
    }
}

// ---------------------------------------------------------------------------
// Kernel B: serial segment pass + output projection (byte-identical to R16 —
// the measured-best final). 16 blocks x 256 threads (4 waves/batch), NSEG=32,
// depth-1 next-segment prefetch.
// ---------------------------------------------------------------------------
__global__ __launch_bounds__(256, 1) void final_kernel(
    const u16* __restrict__ q_ws, const u32* __restrict__ PK,
    const float* __restrict__ Wr, const float* __restrict__ br,
    const float* __restrict__ Wo, const float* __restrict__ bo,
    float* __restrict__ out)
{
    const int b    = blockIdx.x;
    const int t    = threadIdx.x;
    const int lane = t & 63;
    const int p    = t >> 6;         // wave id = j-slice

    __shared__ float psum[4][72];
    __shared__ float rl[64];
    __shared__ float cs[64], rs[64];

    rl[lane] = bf2f(q_ws[b * 64 + lane]);

    float ctxp = 0.f;
    u32 cur[16], nxt[16];
    {
        const u32* pk0 = PK + ((size_t)(b * NSEG + 0) << 12);
#pragma unroll
        for (int jj = 0; jj < 16; ++jj)
            cur[jj] = pk0[(p * 16 + jj) * 64 + lane];
    }
    __syncthreads();

    for (int s = 0; s < NSEG; ++s) {
        const int sn = (s + 1 < NSEG) ? s + 1 : s;
        const u32* pkn = PK + ((size_t)(b * NSEG + sn) << 12);
#pragma unroll
        for (int jj = 0; jj < 16; ++jj)
            nxt[jj] = pkn[(p * 16 + jj) * 64 + lane];

        float accr = 0.f;
#pragma unroll
        for (int jj = 0; jj < 16; ++jj) {
            const u32 pv = cur[jj];
            const float Sv = __uint_as_float(pv & 0xFFFF0000u);
            const float Vv = __uint_as_float(pv << 16);
            const float rj = rl[p * 16 + jj];
            accr = fmaf(Sv, rj, accr);
            ctxp = fmaf(Vv, rj, ctxp);
        }
        psum[p][lane] = accr;
        __syncthreads();
        const float rn = (psum[0][lane] + psum[1][lane]) + (psum[2][lane] + psum[3][lane]);
        __syncthreads();
        rl[lane] = rn;

#pragma unroll
        for (int jj = 0; jj < 16; ++jj) cur[jj] = nxt[jj];
    }

    psum[p][lane] = ctxp;
    __syncthreads();
    if (t < 64)
        cs[t] = (psum[0][t] + psum[1][t]) + (psum[2][t] + psum[3][t]);
    __syncthreads();

    float rv = (p == 0) ? br[lane] : 0.f;
#pragma unroll
    for (int i = 0; i < 16; ++i)
        rv = fmaf(cs[p * 16 + i], Wr[(p * 16 + i) * HDIM + lane], rv);
    psum[p][lane] = rv;
    __syncthreads();
    if (t < 64)
        rs[t] = (psum[0][t] + psum[1][t]) + (psum[2][t] + psum[3][t]);
    __syncthreads();

    float ov = (p == 0) ? bo[lane] : 0.f;
#pragma unroll
    for (int i = 0; i < 16; ++i)
        ov = fmaf(rs[p * 16 + i], Wo[(p * 16 + i) * HDIM + lane], ov);
    psum[p][lane] = ov;
    __syncthreads();
    if (t < 64)
        out[(size_t)b * HDIM + t] = (psum[0][t] + psum[1][t]) + (psum[2][t] + psum[3][t]);
}

// ---------------------------------------------------------------------------
extern "C" void kernel_launch(void* const* d_in, const int* in_sizes, int n_in,
                              void* d_out, int out_size, void* d_ws, size_t ws_size,
                              hipStream_t stream)
{
    const int*   seq   = (const int*)  d_in[0];
    const float* embed = (const float*)d_in[1];
    const float* W1    = (const float*)d_in[2];
    const float* b1    = (const float*)d_in[3];
    const float* W2    = (const float*)d_in[4];
    const float* b2    = (const float*)d_in[5];
    const float* gamma = (const float*)d_in[6];
    const float* beta  = (const float*)d_in[7];
    const float* Wr    = (const float*)d_in[8];
    const float* br    = (const float*)d_in[9];
    const float* Wo    = (const float*)d_in[10];
    const float* bo    = (const float*)d_in[11];

    u32* pk_ws = (u32*)d_ws;                                  // 8 MB (16*32*4096 u32)
    u16* q_ws  = (u16*)(pk_ws + (size_t)BATCH * NSEG * 4096); // 2 KB
    float* outp = (float*)d_out;

    hipLaunchKernelGGL(fused_pc_kernel, dim3(BATCH * NSEG), dim3(256), 0, stream,
                       seq, embed, W1, b1, W2, b2, gamma, beta, pk_ws, q_ws);
    hipLaunchKernelGGL(final_kernel, dim3(BATCH), dim3(256), 0, stream,
                       q_ws, pk_ws, Wr, br, Wo, bo, outp);
}